// Round 11
// baseline (230.037 us; speedup 1.0000x reference)
//
#include <hip/hip_runtime.h>
#include <hip/hip_bf16.h>

#define NE 1600000
#define NN 100000

typedef __attribute__((ext_vector_type(8))) short s16x8;
typedef __attribute__((ext_vector_type(4))) float f32x4;
typedef __attribute__((ext_vector_type(4))) uint u32x4;

__device__ __forceinline__ ushort f2b(float v) {
  union { __hip_bfloat16 h; ushort u; } c; c.h = __float2bfloat16(v); return c.u;
}
// HW packed f32x2 -> bf16x2 (RNE). lo = a, hi = b. Verified on-device (r4-r9).
__device__ __forceinline__ uint cvtpk(float a, float b) {
  uint r;
  asm("v_cvt_pk_bf16_f32 %0, %1, %2" : "=v"(r) : "v"(a), "v"(b));
  return r;
}
__device__ __forceinline__ uint pkrelu(float a, float b) {
  a = fmaxf(a, 0.f); b = fmaxf(b, 0.f);
  return cvtpk(a, b);
}
// MFMA with A pinned to AGPR, consumed in place (no accvgpr_read copies).
// Inline asm bypasses the compiler's hazard recognizer, so wait states are
// manual (r10 lesson): prefix s_nop 1 covers VALU-write->MFMA-read; suffix
// s_nop 7 + s_nop 2 on chain-final MFMAs covers MFMA-D-write->VALU-read.
// Same-D MFMA->MFMA chains need none (m119 dependent-chain peak).
__device__ __forceinline__ f32x4 mfma_init(s16x8 a, s16x8 b, f32x4 c) {
  f32x4 d;
  asm("s_nop 1\n\tv_mfma_f32_16x16x32_bf16 %0, %1, %2, %3"
      : "=&v"(d) : "a"(a), "v"(b), "v"(c));
  return d;
}
__device__ __forceinline__ f32x4 mfma_init_end(s16x8 a, s16x8 b, f32x4 c) {
  f32x4 d;
  asm("s_nop 1\n\tv_mfma_f32_16x16x32_bf16 %0, %1, %2, %3\n\ts_nop 7\n\ts_nop 2"
      : "=&v"(d) : "a"(a), "v"(b), "v"(c));
  return d;
}
__device__ __forceinline__ void mfma_acc(f32x4& d, s16x8 a, s16x8 b) {
  asm("s_nop 1\n\tv_mfma_f32_16x16x32_bf16 %0, %1, %2, %0"
      : "+v"(d) : "a"(a), "v"(b));
}
__device__ __forceinline__ void mfma_acc_end(f32x4& d, s16x8 a, s16x8 b) {
  asm("s_nop 1\n\tv_mfma_f32_16x16x32_bf16 %0, %1, %2, %0\n\ts_nop 7\n\ts_nop 2"
      : "+v"(d) : "a"(a), "v"(b));
}

// ---- prep: identical to r7-r10 (verified). Weights -> MFMA fragment order (bf16).
__global__ void prep_weights(const float* s0, const float* s1, const float* s2, const float* s3,
                             const float* s4, const float* s5, const float* s6, const float* s7,
                             const float* bm0, const float* bu0, ushort* dst) {
  const int Ks[8]   = {10, 128, 128, 128, 7, 128, 128, 128};
  const int Ns[8]   = {128, 128, 128, 2, 128, 128, 128, 2};
  const int NFs[8]  = {8, 8, 8, 1, 8, 8, 8, 1};
  const int KCs[8]  = {1, 4, 4, 4, 1, 4, 4, 4};
  const int offs[8] = {0, 4096, 20480, 36864, 38912, 43008, 59392, 75776};
  const float* srcs[8] = {s0, s1, s2, s3, s4, s5, s6, s7};
  int b = blockIdx.x;
  int K = Ks[b], N = Ns[b], NF = NFs[b];
  int cnt = KCs[b] * NF * 512;
  const float* src = srcs[b];
  bool isProducer = (b == 0 || b == 4);
  int F1 = (b == 0) ? 5 : 2;
  int kbias = (b == 0) ? 13 : 10;
  const float* bp = (b == 0) ? bm0 : bu0;
  ushort* d = dst + offs[b];
  for (int idx = threadIdx.x; idx < cnt; idx += blockDim.x) {
    int f = idx >> 9, r = idx & 511, lane = r >> 3, j = r & 7;
    int kb = f / NF, nb = f - kb * NF;
    int k = kb * 32 + ((lane >> 4) << 3) + j;
    int n = (nb << 4) + (lane & 15);
    float v = 0.f;
    if (n < N) {
      if (isProducer) {
        int row = -1;
        if (k < 5) row = k;
        else if (k >= 8 && k < 8 + F1) row = k - 3;
        if (row >= 0 && row < K) v = src[row * N + n];
        else if (k == kbias) v = bp[n];
      } else {
        int ks = (k & 96) | ((k & 4) << 2) | ((k & 24) >> 1) | (k & 3);
        if (ks < K) v = src[ks * N + n];
      }
    }
    d[idx] = f2b(v);
  }
}

// ---- main: wave-specialized pipeline (r9 structure, verified). 8 waves/block:
// waves 0-3 = FRONT (L0+L1), waves 4-7 = BACK (L2+head); pair shares a SIMD.
// Weights AGPR-resident, consumed in place by hazard-hardened inline-asm MFMA.
template <int MODE>
__global__ __launch_bounds__(512, 2)
void gnn_kernel(const float* __restrict__ nodes,
                const int* __restrict__ eidx,
                float* __restrict__ pooled,
                const ushort* __restrict__ wsrc,
                const float* __restrict__ b1g, const float* __restrict__ b2g,
                const float* __restrict__ b3g,
                float* __restrict__ out) {
  __shared__ __align__(16) char hand[65536];     // 4 pairs x 2 bufs x 8192 B
  __shared__ __align__(16) float bias1[128];
  __shared__ __align__(16) float bias2[128];
  __shared__ __align__(16) float bias3[16];
  if (threadIdx.x < 128) {
    bias1[threadIdx.x] = b1g[threadIdx.x];
    bias2[threadIdx.x] = b2g[threadIdx.x];
  }
  if (threadIdx.x < 16) bias3[threadIdx.x] = (threadIdx.x < 2) ? b3g[threadIdx.x] : 0.f;

  const int wv = threadIdx.x >> 6;
  const int l = threadIdx.x & 63;
  const int q = l >> 4;
  const int m16 = l & 15;
  const bool front = (wv < 4);
  const int pr = wv & 3;
  char* hbase = hand + pr * 16384;

  // ---- unioned weight registers: front={W0,W1}, back={W3,W2} ----
  s16x8 Wx[8];     // front: W0[ht] ; back: W3[kb] in Wx[0..3]
  s16x8 W[4][8];   // front: W1[kb][ht] ; back: W2[kb][ht]
  if (front) {
#pragma unroll
    for (int ht = 0; ht < 8; ht++)
      Wx[ht] = *(const s16x8*)(wsrc + (((ht << 6) + l) << 3));
#pragma unroll
    for (int kb = 0; kb < 4; kb++)
#pragma unroll
      for (int ht = 0; ht < 8; ht++)
        W[kb][ht] = *(const s16x8*)(wsrc + 4096 + ((((kb << 3) + ht) << 6) + l) * 8);
  } else {
#pragma unroll
    for (int kb = 0; kb < 4; kb++)
      Wx[kb] = *(const s16x8*)(wsrc + 36864 + (((kb << 6) + l) << 3));
#pragma unroll
    for (int kb = 0; kb < 4; kb++)
#pragma unroll
      for (int ht = 0; ht < 8; ht++)
        W[kb][ht] = *(const s16x8*)(wsrc + 20480 + ((((kb << 3) + ht) << 6) + l) * 8);
  }
  __syncthreads();

  const int np = gridDim.x << 2;                  // pairs total
  const int gp = (blockIdx.x << 2) + pr;          // this pair's id
  const int NB = (MODE == 0) ? (NE / 32) : (NN / 32);
  const int niter = (NB + np - 1) / np;

  // gather prefetch (front only): lane (q,m16) owns k-slots q*8.. of edges et*16+m16
  float gf[2][5] = {{0.f, 0.f, 0.f, 0.f, 0.f}, {0.f, 0.f, 0.f, 0.f, 0.f}};
  auto PREF = [&](int bb) {
    if (bb < NB && q < 2) {
#pragma unroll
      for (int et = 0; et < 2; et++) {
        int e = (bb << 5) + (et << 4) + m16;
        if (MODE == 0) {
          int idx = eidx[q * NE + e];
          const float* np_ = nodes + idx * 5;
          gf[et][0] = np_[0]; gf[et][1] = np_[1]; gf[et][2] = np_[2];
          gf[et][3] = np_[3]; gf[et][4] = np_[4];
        } else {
          if (q == 0) {
            const float* np_ = nodes + e * 5;
            gf[et][0] = np_[0]; gf[et][1] = np_[1]; gf[et][2] = np_[2];
            gf[et][3] = np_[3]; gf[et][4] = np_[4];
          } else {
            float2 pl = *(const float2*)&pooled[e * 2];
            gf[et][0] = pl.x; gf[et][1] = pl.y;
          }
        }
      }
    }
  };
  if (front) PREF(gp);
  const f32x4 zero4 = {0.f, 0.f, 0.f, 0.f};

#pragma unroll 1
  for (int t = 0; t <= niter; ++t) {
    if (front) {
      int b = gp + t * np;
      if (t < niter && b < NB) {
        // build layer-0 B-fragments from prefetched gather
        s16x8 xf[2];
#pragma unroll
        for (int et = 0; et < 2; et++) {
          u32x4 f = {0u, 0u, 0u, 0u};
          if (q == 0) {
            f[0] = cvtpk(gf[et][0], gf[et][1]);
            f[1] = cvtpk(gf[et][2], gf[et][3]);
            f[2] = cvtpk(gf[et][4], 0.f);
          } else if (q == 1) {
            if (MODE == 0) {
              f[0] = cvtpk(gf[et][0], gf[et][1]);
              f[1] = cvtpk(gf[et][2], gf[et][3]);
              f[2] = cvtpk(gf[et][4], 1.0f);     // bias rides k13
            } else {
              f[0] = cvtpk(gf[et][0], gf[et][1]);
              f[1] = cvtpk(1.0f, 0.f);            // bias rides k10
            }
          }
          xf[et] = __builtin_bit_cast(s16x8, f);
        }
        PREF(b + np);

        // L0: K=32, bias folded into W0 (direct-read MFMAs -> _end form)
        u32x4 ph[4][2];
#pragma unroll
        for (int ht = 0; ht < 8; ht++) {
          f32x4 a0 = mfma_init_end(Wx[ht], xf[0], zero4);
          f32x4 a1 = mfma_init_end(Wx[ht], xf[1], zero4);
          ph[ht >> 1][0][2 * (ht & 1)]     = pkrelu(a0[0], a0[1]);
          ph[ht >> 1][0][2 * (ht & 1) + 1] = pkrelu(a0[2], a0[3]);
          ph[ht >> 1][1][2 * (ht & 1)]     = pkrelu(a1[0], a1[1]);
          ph[ht >> 1][1][2 * (ht & 1) + 1] = pkrelu(a1[2], a1[3]);
        }
        // L1 -> H2, written incrementally to LDS buf[t&1]
        char* wb = hbase + (t & 1) * 8192;
        u32x4 hold[2];
#pragma unroll
        for (int ht = 0; ht < 8; ht++) {
          f32x4 bf = *(const f32x4*)(bias1 + (ht << 4) + (q << 2));
          f32x4 a0 = mfma_init(W[0][ht], __builtin_bit_cast(s16x8, ph[0][0]), bf);
          f32x4 a1 = mfma_init(W[0][ht], __builtin_bit_cast(s16x8, ph[0][1]), bf);
#pragma unroll
          for (int kb = 1; kb < 3; kb++) {
            mfma_acc(a0, W[kb][ht], __builtin_bit_cast(s16x8, ph[kb][0]));
            mfma_acc(a1, W[kb][ht], __builtin_bit_cast(s16x8, ph[kb][1]));
          }
          mfma_acc_end(a0, W[3][ht], __builtin_bit_cast(s16x8, ph[3][0]));
          mfma_acc_end(a1, W[3][ht], __builtin_bit_cast(s16x8, ph[3][1]));
          hold[0][2 * (ht & 1)]     = pkrelu(a0[0], a0[1]);
          hold[0][2 * (ht & 1) + 1] = pkrelu(a0[2], a0[3]);
          hold[1][2 * (ht & 1)]     = pkrelu(a1[0], a1[1]);
          hold[1][2 * (ht & 1) + 1] = pkrelu(a1[2], a1[3]);
          if (ht & 1) {
            int kg = ht >> 1;
            *(u32x4*)(wb + ((kg << 1) + 0) * 1024 + l * 16) = hold[0];
            *(u32x4*)(wb + ((kg << 1) + 1) * 1024 + l * 16) = hold[1];
          }
        }
      }
    } else {
      int bc = gp + (t - 1) * np;
      if (t >= 1 && bc < NB) {
        const int rbase = bc << 5;
        int rc0 = 0, rc1 = 0;
        if (MODE == 0 && q == 0) {
          rc0 = eidx[NE + rbase + m16];
          rc1 = eidx[NE + rbase + 16 + m16];
        }
        // read H2 fragments from LDS buf[(t-1)&1]
        const char* rb = hbase + ((t - 1) & 1) * 8192;
        u32x4 pin[4][2];
#pragma unroll
        for (int kb = 0; kb < 4; kb++) {
          pin[kb][0] = *(const u32x4*)(rb + ((kb << 1) + 0) * 1024 + l * 16);
          pin[kb][1] = *(const u32x4*)(rb + ((kb << 1) + 1) * 1024 + l * 16);
        }
        // L2: pin -> ph
        u32x4 ph[4][2];
#pragma unroll
        for (int ht = 0; ht < 8; ht++) {
          f32x4 bf = *(const f32x4*)(bias2 + (ht << 4) + (q << 2));
          f32x4 a0 = mfma_init(W[0][ht], __builtin_bit_cast(s16x8, pin[0][0]), bf);
          f32x4 a1 = mfma_init(W[0][ht], __builtin_bit_cast(s16x8, pin[0][1]), bf);
#pragma unroll
          for (int kb = 1; kb < 3; kb++) {
            mfma_acc(a0, W[kb][ht], __builtin_bit_cast(s16x8, pin[kb][0]));
            mfma_acc(a1, W[kb][ht], __builtin_bit_cast(s16x8, pin[kb][1]));
          }
          mfma_acc_end(a0, W[3][ht], __builtin_bit_cast(s16x8, pin[3][0]));
          mfma_acc_end(a1, W[3][ht], __builtin_bit_cast(s16x8, pin[3][1]));
          ph[ht >> 1][0][2 * (ht & 1)]     = pkrelu(a0[0], a0[1]);
          ph[ht >> 1][0][2 * (ht & 1) + 1] = pkrelu(a0[2], a0[3]);
          ph[ht >> 1][1][2 * (ht & 1)]     = pkrelu(a1[0], a1[1]);
          ph[ht >> 1][1][2 * (ht & 1) + 1] = pkrelu(a1[2], a1[3]);
        }
        // head: K=128, N=2 (rows 0,1 -> q==0), W3 = Wx[0..3]
        f32x4 b3f = *(const f32x4*)(bias3 + (q << 2));
        f32x4 ah[2];
#pragma unroll
        for (int et = 0; et < 2; et++) {
          f32x4 a = mfma_init(Wx[0], __builtin_bit_cast(s16x8, ph[0][et]), b3f);
          mfma_acc(a, Wx[1], __builtin_bit_cast(s16x8, ph[1][et]));
          mfma_acc(a, Wx[2], __builtin_bit_cast(s16x8, ph[2][et]));
          mfma_acc_end(a, Wx[3], __builtin_bit_cast(s16x8, ph[3][et]));
          ah[et] = a;
        }
        if (q == 0) {
#pragma unroll
          for (int et = 0; et < 2; et++) {
            int e = rbase + (et << 4) + m16;
            float mv0 = ah[et][0], mv1 = ah[et][1];
            if (MODE == 0) {
              int rc = et ? rc1 : rc0;
              unsafeAtomicAdd(&pooled[rc * 2], mv0);
              unsafeAtomicAdd(&pooled[rc * 2 + 1], mv1);
            } else {
              out[e * 5 + 2] = nodes[e * 5 + 2] + mv0;
              out[e * 5 + 3] = nodes[e * 5 + 3] + mv1;
            }
          }
        } else if (MODE == 1 && q == 1) {
#pragma unroll
          for (int et = 0; et < 2; et++) {
            int e = rbase + (et << 4) + m16;
            out[e * 5] = nodes[e * 5]; out[e * 5 + 1] = nodes[e * 5 + 1];
          }
        } else if (MODE == 1 && q == 2) {
#pragma unroll
          for (int et = 0; et < 2; et++) {
            int e = rbase + (et << 4) + m16;
            out[e * 5 + 4] = nodes[e * 5 + 4];
          }
        }
      }
    }
    __syncthreads();
  }
}

extern "C" void kernel_launch(void* const* d_in, const int* in_sizes, int n_in,
                              void* d_out, int out_size, void* d_ws, size_t ws_size,
                              hipStream_t stream) {
  const float* nodes = (const float*)d_in[0];
  const int* eidx = (const int*)d_in[1];
  const float* Wm0 = (const float*)d_in[2];  const float* bm0 = (const float*)d_in[3];
  const float* Wm1 = (const float*)d_in[4];  const float* bm1 = (const float*)d_in[5];
  const float* Wm2 = (const float*)d_in[6];  const float* bm2 = (const float*)d_in[7];
  const float* Wm3 = (const float*)d_in[8];  const float* bm3 = (const float*)d_in[9];
  const float* Wu0 = (const float*)d_in[10]; const float* bu0 = (const float*)d_in[11];
  const float* Wu1 = (const float*)d_in[12]; const float* bu1 = (const float*)d_in[13];
  const float* Wu2 = (const float*)d_in[14]; const float* bu2 = (const float*)d_in[15];
  const float* Wu3 = (const float*)d_in[16]; const float* bu3 = (const float*)d_in[17];

  float* pooled = (float*)d_ws;                     // NN*2 f32 = 800000 B
  ushort* wbuf = (ushort*)((char*)d_ws + 800000);   // 2*38912 prearranged bf16

  hipMemsetAsync(pooled, 0, NN * 2 * sizeof(float), stream);
  prep_weights<<<8, 256, 0, stream>>>(Wm0, Wm1, Wm2, Wm3, Wu0, Wu1, Wu2, Wu3,
                                      bm0, bu0, wbuf);

  gnn_kernel<0><<<256, 512, 0, stream>>>(nodes, eidx, pooled, wbuf,
                                         bm1, bm2, bm3, nullptr);
  gnn_kernel<1><<<256, 512, 0, stream>>>(nodes, nullptr, pooled, wbuf + 38912,
                                         bu1, bu2, bu3, (float*)d_out);
}

// Round 12
// 219.918 us; speedup vs baseline: 1.0460x; 1.0460x over previous
//
#include <hip/hip_runtime.h>
#include <hip/hip_bf16.h>

#define NE 1600000
#define NN 100000

typedef __attribute__((ext_vector_type(8))) short s16x8;
typedef __attribute__((ext_vector_type(4))) float f32x4;
typedef __attribute__((ext_vector_type(4))) uint u32x4;

__device__ __forceinline__ ushort f2b(float v) {
  union { __hip_bfloat16 h; ushort u; } c; c.h = __float2bfloat16(v); return c.u;
}
// HW packed f32x2 -> bf16x2 (RNE). lo = a, hi = b. Verified on-device (r4-r11).
__device__ __forceinline__ uint cvtpk(float a, float b) {
  uint r;
  asm("v_cvt_pk_bf16_f32 %0, %1, %2" : "=v"(r) : "v"(a), "v"(b));
  return r;
}
__device__ __forceinline__ uint pkrelu(float a, float b) {
  a = fmaxf(a, 0.f); b = fmaxf(b, 0.f);
  return cvtpk(a, b);
}

// ---- prep: identical to r7-r11 (verified). Weights -> MFMA fragment order (bf16).
__global__ void prep_weights(const float* s0, const float* s1, const float* s2, const float* s3,
                             const float* s4, const float* s5, const float* s6, const float* s7,
                             const float* bm0, const float* bu0, ushort* dst) {
  const int Ks[8]   = {10, 128, 128, 128, 7, 128, 128, 128};
  const int Ns[8]   = {128, 128, 128, 2, 128, 128, 128, 2};
  const int NFs[8]  = {8, 8, 8, 1, 8, 8, 8, 1};
  const int KCs[8]  = {1, 4, 4, 4, 1, 4, 4, 4};
  const int offs[8] = {0, 4096, 20480, 36864, 38912, 43008, 59392, 75776};
  const float* srcs[8] = {s0, s1, s2, s3, s4, s5, s6, s7};
  int b = blockIdx.x;
  int K = Ks[b], N = Ns[b], NF = NFs[b];
  int cnt = KCs[b] * NF * 512;
  const float* src = srcs[b];
  bool isProducer = (b == 0 || b == 4);
  int F1 = (b == 0) ? 5 : 2;
  int kbias = (b == 0) ? 13 : 10;
  const float* bp = (b == 0) ? bm0 : bu0;
  ushort* d = dst + offs[b];
  for (int idx = threadIdx.x; idx < cnt; idx += blockDim.x) {
    int f = idx >> 9, r = idx & 511, lane = r >> 3, j = r & 7;
    int kb = f / NF, nb = f - kb * NF;
    int k = kb * 32 + ((lane >> 4) << 3) + j;
    int n = (nb << 4) + (lane & 15);
    float v = 0.f;
    if (n < N) {
      if (isProducer) {
        int row = -1;
        if (k < 5) row = k;
        else if (k >= 8 && k < 8 + F1) row = k - 3;
        if (row >= 0 && row < K) v = src[row * N + n];
        else if (k == kbias) v = bp[n];
      } else {
        int ks = (k & 96) | ((k & 4) << 2) | ((k & 24) >> 1) | (k & 3);
        if (ks < K) v = src[ks * N + n];
      }
    }
    d[idx] = f2b(v);
  }
}

// ---- main: wave-specialized pipeline (r9 compute, verified) with PAIR-LOCAL
// LDS flag sync instead of block-wide __syncthreads: no vmcnt drain, pairs
// decoupled, waves wait only when data-starved. prod/cons monotonic counters,
// depth-2 over the double buffer. DS ops are program-ordered per wave;
// sched_barrier(0) pins program order around flag ops (rule #18).
template <int MODE>
__global__ __launch_bounds__(512, 2)
void gnn_kernel(const float* __restrict__ nodes,
                const int* __restrict__ eidx,
                float* __restrict__ pooled,
                const ushort* __restrict__ wsrc,
                const float* __restrict__ b1g, const float* __restrict__ b2g,
                const float* __restrict__ b3g,
                float* __restrict__ out) {
  __shared__ __align__(16) char hand[65536];     // 4 pairs x 2 bufs x 8192 B
  __shared__ __align__(16) float bias1[128];
  __shared__ __align__(16) float bias2[128];
  __shared__ __align__(16) float bias3[16];
  __shared__ uint flags[64];                     // prod[pr]=flags[pr*8], cons[pr]=flags[32+pr*8]
  if (threadIdx.x < 128) {
    bias1[threadIdx.x] = b1g[threadIdx.x];
    bias2[threadIdx.x] = b2g[threadIdx.x];
  }
  if (threadIdx.x < 16) bias3[threadIdx.x] = (threadIdx.x < 2) ? b3g[threadIdx.x] : 0.f;
  if (threadIdx.x < 64) flags[threadIdx.x] = 0u;

  const int wv = threadIdx.x >> 6;
  const int l = threadIdx.x & 63;
  const int q = l >> 4;
  const int m16 = l & 15;
  const bool front = (wv < 4);
  const int pr = wv & 3;
  char* hbase = hand + pr * 16384;
  volatile uint* prodv = &flags[pr * 8];
  volatile uint* consv = &flags[32 + pr * 8];

  // ---- unioned weight registers: front={W0,W1}, back={W3,W2} ----
  s16x8 Wx[8];     // front: W0[ht] ; back: W3[kb] in Wx[0..3]
  s16x8 W[4][8];   // front: W1[kb][ht] ; back: W2[kb][ht]
  if (front) {
#pragma unroll
    for (int ht = 0; ht < 8; ht++)
      Wx[ht] = *(const s16x8*)(wsrc + (((ht << 6) + l) << 3));
#pragma unroll
    for (int kb = 0; kb < 4; kb++)
#pragma unroll
      for (int ht = 0; ht < 8; ht++)
        W[kb][ht] = *(const s16x8*)(wsrc + 4096 + ((((kb << 3) + ht) << 6) + l) * 8);
  } else {
#pragma unroll
    for (int kb = 0; kb < 4; kb++)
      Wx[kb] = *(const s16x8*)(wsrc + 36864 + (((kb << 6) + l) << 3));
#pragma unroll
    for (int kb = 0; kb < 4; kb++)
#pragma unroll
      for (int ht = 0; ht < 8; ht++)
        W[kb][ht] = *(const s16x8*)(wsrc + 20480 + ((((kb << 3) + ht) << 6) + l) * 8);
  }
  __syncthreads();   // one-time: weights/bias/flags visible to all

  const int np = gridDim.x << 2;                  // pairs total
  const int gp = (blockIdx.x << 2) + pr;          // this pair's id
  const int NB = (MODE == 0) ? (NE / 32) : (NN / 32);

  if (front) {
    // gather prefetch: lane (q,m16) owns k-slots q*8.. of edges et*16+m16
    float gf[2][5] = {{0.f, 0.f, 0.f, 0.f, 0.f}, {0.f, 0.f, 0.f, 0.f, 0.f}};
    auto PREF = [&](int bb) {
      if (bb < NB && q < 2) {
#pragma unroll
        for (int et = 0; et < 2; et++) {
          int e = (bb << 5) + (et << 4) + m16;
          if (MODE == 0) {
            int idx = eidx[q * NE + e];
            const float* np_ = nodes + idx * 5;
            gf[et][0] = np_[0]; gf[et][1] = np_[1]; gf[et][2] = np_[2];
            gf[et][3] = np_[3]; gf[et][4] = np_[4];
          } else {
            if (q == 0) {
              const float* np_ = nodes + e * 5;
              gf[et][0] = np_[0]; gf[et][1] = np_[1]; gf[et][2] = np_[2];
              gf[et][3] = np_[3]; gf[et][4] = np_[4];
            } else {
              float2 pl = *(const float2*)&pooled[e * 2];
              gf[et][0] = pl.x; gf[et][1] = pl.y;
            }
          }
        }
      }
    };
    PREF(gp);
    const f32x4 zero4 = {0.f, 0.f, 0.f, 0.f};

    int t = 0;
#pragma unroll 1
    for (int b = gp; b < NB; b += np, ++t) {
      // build layer-0 B-fragments from prefetched gather
      s16x8 xf[2];
#pragma unroll
      for (int et = 0; et < 2; et++) {
        u32x4 f = {0u, 0u, 0u, 0u};
        if (q == 0) {
          f[0] = cvtpk(gf[et][0], gf[et][1]);
          f[1] = cvtpk(gf[et][2], gf[et][3]);
          f[2] = cvtpk(gf[et][4], 0.f);
        } else if (q == 1) {
          if (MODE == 0) {
            f[0] = cvtpk(gf[et][0], gf[et][1]);
            f[1] = cvtpk(gf[et][2], gf[et][3]);
            f[2] = cvtpk(gf[et][4], 1.0f);     // bias rides k13
          } else {
            f[0] = cvtpk(gf[et][0], gf[et][1]);
            f[1] = cvtpk(1.0f, 0.f);            // bias rides k10
          }
        }
        xf[et] = __builtin_bit_cast(s16x8, f);
      }
      PREF(b + np);

      // L0: K=32, bias folded into W0
      u32x4 ph[4][2];
#pragma unroll
      for (int ht = 0; ht < 8; ht++) {
        f32x4 a0 = __builtin_amdgcn_mfma_f32_16x16x32_bf16(Wx[ht], xf[0], zero4, 0, 0, 0);
        f32x4 a1 = __builtin_amdgcn_mfma_f32_16x16x32_bf16(Wx[ht], xf[1], zero4, 0, 0, 0);
        ph[ht >> 1][0][2 * (ht & 1)]     = pkrelu(a0[0], a0[1]);
        ph[ht >> 1][0][2 * (ht & 1) + 1] = pkrelu(a0[2], a0[3]);
        ph[ht >> 1][1][2 * (ht & 1)]     = pkrelu(a1[0], a1[1]);
        ph[ht >> 1][1][2 * (ht & 1) + 1] = pkrelu(a1[2], a1[3]);
      }
      // wait until back consumed buf[t&1] (from iter t-2)
      if (t >= 2) {
        while (*consv < (uint)(t - 1)) __builtin_amdgcn_s_sleep(1);
        __builtin_amdgcn_sched_barrier(0);
      }
      // L1 -> H2, written incrementally to LDS buf[t&1]
      char* wb = hbase + (t & 1) * 8192;
      u32x4 hold[2];
#pragma unroll
      for (int ht = 0; ht < 8; ht++) {
        f32x4 bf = *(const f32x4*)(bias1 + (ht << 4) + (q << 2));
        f32x4 a0 = __builtin_amdgcn_mfma_f32_16x16x32_bf16(
            W[0][ht], __builtin_bit_cast(s16x8, ph[0][0]), bf, 0, 0, 0);
        f32x4 a1 = __builtin_amdgcn_mfma_f32_16x16x32_bf16(
            W[0][ht], __builtin_bit_cast(s16x8, ph[0][1]), bf, 0, 0, 0);
#pragma unroll
        for (int kb = 1; kb < 4; kb++) {
          a0 = __builtin_amdgcn_mfma_f32_16x16x32_bf16(
              W[kb][ht], __builtin_bit_cast(s16x8, ph[kb][0]), a0, 0, 0, 0);
          a1 = __builtin_amdgcn_mfma_f32_16x16x32_bf16(
              W[kb][ht], __builtin_bit_cast(s16x8, ph[kb][1]), a1, 0, 0, 0);
        }
        hold[0][2 * (ht & 1)]     = pkrelu(a0[0], a0[1]);
        hold[0][2 * (ht & 1) + 1] = pkrelu(a0[2], a0[3]);
        hold[1][2 * (ht & 1)]     = pkrelu(a1[0], a1[1]);
        hold[1][2 * (ht & 1) + 1] = pkrelu(a1[2], a1[3]);
        if (ht & 1) {
          int kg = ht >> 1;
          *(u32x4*)(wb + ((kg << 1) + 0) * 1024 + l * 16) = hold[0];
          *(u32x4*)(wb + ((kg << 1) + 1) * 1024 + l * 16) = hold[1];
        }
      }
      // publish: buf[t&1] ready (DS ops are program-ordered per wave)
      __builtin_amdgcn_sched_barrier(0);
      if (l == 0) *prodv = (uint)(t + 1);
      __builtin_amdgcn_sched_barrier(0);
    }
  } else {
    int bc = 0;
#pragma unroll 1
    for (int b = gp; b < NB; b += np, ++bc) {
      const int rbase = b << 5;
      int rc0 = 0, rc1 = 0;
      if (MODE == 0 && q == 0) {
        rc0 = eidx[NE + rbase + m16];
        rc1 = eidx[NE + rbase + 16 + m16];
      }
      // wait until front produced buf[bc&1]
      while (*prodv < (uint)(bc + 1)) __builtin_amdgcn_s_sleep(1);
      __builtin_amdgcn_sched_barrier(0);
      // read H2 fragments from LDS buf[bc&1]
      const char* rb = hbase + (bc & 1) * 8192;
      u32x4 pin[4][2];
#pragma unroll
      for (int kb = 0; kb < 4; kb++) {
        pin[kb][0] = *(const u32x4*)(rb + ((kb << 1) + 0) * 1024 + l * 16);
        pin[kb][1] = *(const u32x4*)(rb + ((kb << 1) + 1) * 1024 + l * 16);
      }
      // release the buffer as soon as the data is in registers
      __builtin_amdgcn_sched_barrier(0);
      if (l == 0) *consv = (uint)(bc + 1);
      __builtin_amdgcn_sched_barrier(0);
      // L2: pin -> ph
      u32x4 ph[4][2];
#pragma unroll
      for (int ht = 0; ht < 8; ht++) {
        f32x4 bf = *(const f32x4*)(bias2 + (ht << 4) + (q << 2));
        f32x4 a0 = __builtin_amdgcn_mfma_f32_16x16x32_bf16(
            W[0][ht], __builtin_bit_cast(s16x8, pin[0][0]), bf, 0, 0, 0);
        f32x4 a1 = __builtin_amdgcn_mfma_f32_16x16x32_bf16(
            W[0][ht], __builtin_bit_cast(s16x8, pin[0][1]), bf, 0, 0, 0);
#pragma unroll
        for (int kb = 1; kb < 4; kb++) {
          a0 = __builtin_amdgcn_mfma_f32_16x16x32_bf16(
              W[kb][ht], __builtin_bit_cast(s16x8, pin[kb][0]), a0, 0, 0, 0);
          a1 = __builtin_amdgcn_mfma_f32_16x16x32_bf16(
              W[kb][ht], __builtin_bit_cast(s16x8, pin[kb][1]), a1, 0, 0, 0);
        }
        ph[ht >> 1][0][2 * (ht & 1)]     = pkrelu(a0[0], a0[1]);
        ph[ht >> 1][0][2 * (ht & 1) + 1] = pkrelu(a0[2], a0[3]);
        ph[ht >> 1][1][2 * (ht & 1)]     = pkrelu(a1[0], a1[1]);
        ph[ht >> 1][1][2 * (ht & 1) + 1] = pkrelu(a1[2], a1[3]);
      }
      // head: K=128, N=2 (rows 0,1 -> q==0), W3 = Wx[0..3]
      f32x4 b3f = *(const f32x4*)(bias3 + (q << 2));
      f32x4 ah[2];
#pragma unroll
      for (int et = 0; et < 2; et++) {
        f32x4 a = __builtin_amdgcn_mfma_f32_16x16x32_bf16(
            Wx[0], __builtin_bit_cast(s16x8, ph[0][et]), b3f, 0, 0, 0);
#pragma unroll
        for (int kb = 1; kb < 4; kb++)
          a = __builtin_amdgcn_mfma_f32_16x16x32_bf16(
              Wx[kb], __builtin_bit_cast(s16x8, ph[kb][et]), a, 0, 0, 0);
        ah[et] = a;
      }
      if (q == 0) {
#pragma unroll
        for (int et = 0; et < 2; et++) {
          int e = rbase + (et << 4) + m16;
          float mv0 = ah[et][0], mv1 = ah[et][1];
          if (MODE == 0) {
            int rc = et ? rc1 : rc0;
            unsafeAtomicAdd(&pooled[rc * 2], mv0);
            unsafeAtomicAdd(&pooled[rc * 2 + 1], mv1);
          } else {
            out[e * 5 + 2] = nodes[e * 5 + 2] + mv0;
            out[e * 5 + 3] = nodes[e * 5 + 3] + mv1;
          }
        }
      } else if (MODE == 1 && q == 1) {
#pragma unroll
        for (int et = 0; et < 2; et++) {
          int e = rbase + (et << 4) + m16;
          out[e * 5] = nodes[e * 5]; out[e * 5 + 1] = nodes[e * 5 + 1];
        }
      } else if (MODE == 1 && q == 2) {
#pragma unroll
        for (int et = 0; et < 2; et++) {
          int e = rbase + (et << 4) + m16;
          out[e * 5 + 4] = nodes[e * 5 + 4];
        }
      }
    }
  }
}

extern "C" void kernel_launch(void* const* d_in, const int* in_sizes, int n_in,
                              void* d_out, int out_size, void* d_ws, size_t ws_size,
                              hipStream_t stream) {
  const float* nodes = (const float*)d_in[0];
  const int* eidx = (const int*)d_in[1];
  const float* Wm0 = (const float*)d_in[2];  const float* bm0 = (const float*)d_in[3];
  const float* Wm1 = (const float*)d_in[4];  const float* bm1 = (const float*)d_in[5];
  const float* Wm2 = (const float*)d_in[6];  const float* bm2 = (const float*)d_in[7];
  const float* Wm3 = (const float*)d_in[8];  const float* bm3 = (const float*)d_in[9];
  const float* Wu0 = (const float*)d_in[10]; const float* bu0 = (const float*)d_in[11];
  const float* Wu1 = (const float*)d_in[12]; const float* bu1 = (const float*)d_in[13];
  const float* Wu2 = (const float*)d_in[14]; const float* bu2 = (const float*)d_in[15];
  const float* Wu3 = (const float*)d_in[16]; const float* bu3 = (const float*)d_in[17];

  float* pooled = (float*)d_ws;                     // NN*2 f32 = 800000 B
  ushort* wbuf = (ushort*)((char*)d_ws + 800000);   // 2*38912 prearranged bf16

  hipMemsetAsync(pooled, 0, NN * 2 * sizeof(float), stream);
  prep_weights<<<8, 256, 0, stream>>>(Wm0, Wm1, Wm2, Wm3, Wu0, Wu1, Wu2, Wu3,
                                      bm0, bu0, wbuf);

  gnn_kernel<0><<<256, 512, 0, stream>>>(nodes, eidx, pooled, wbuf,
                                         bm1, bm2, bm3, nullptr);
  gnn_kernel<1><<<256, 512, 0, stream>>>(nodes, nullptr, pooled, wbuf + 38912,
                                         bu1, bu2, bu3, (float*)d_out);
}